// Round 3
// baseline (169.077 us; speedup 1.0000x reference)
//
#include <hip/hip_runtime.h>

// HetConv via bf16 MFMA implicit GEMM, v3.
//  - Weights pre-packed by a prepass into per-lane MFMA A-fragments in d_ws;
//    main kernel loads them DIRECTLY from global (L2-hot, 384 KB total) -- no LDS staging.
//  - x tile double-buffered in LDS; 2-phase pipeline: issue loads(t+1), compute(t),
//    cvt+write(t+1), one barrier per chunk.
//  - LDS x layout [r][c 0..65][icpad 36], 72 B row stride: b-frag = 2x ds_read_b64,
//    bank-uniform (start bank (18*lrow+4*kc)%32 covers all banks exactly 4x).

#define IN_C  256
#define OUT_C 256
#define HH    64
#define WW    64

typedef __attribute__((ext_vector_type(8))) short bf16x8;
typedef __attribute__((ext_vector_type(4))) short bf16x4;
typedef __attribute__((ext_vector_type(4))) float f32x4;

__device__ __forceinline__ unsigned short f2bf(float f) {
    union { float f; unsigned int u; } v; v.f = f;
    unsigned int r = (v.u + 0x7FFFu + ((v.u >> 16) & 1u)) >> 16;
    return (unsigned short)r;
}

// ---------------- weight prepass ----------------
// AH: [h(8)][p(256)][kc(4)][e(8)]  (65536 elems)  A-frag rows for part A (W_hat)
// AK: offset 65536: [h(8)][tf(8)][lo(64)][kc(4)][e(8)] (131072 elems) part B taps
//   h = h2*4+g ; i = kc*8+e ; j = g + 4*(32*h2 + i) ; tap_full = tf<4 ? tf : tf+1
__global__ __launch_bounds__(256)
void hetconv_prep(const float* __restrict__ Wk, const float* __restrict__ W1,
                  unsigned short* __restrict__ ws16) {
    const int TOTAL = 65536 + 131072;
    for (int idx = blockIdx.x * 256 + threadIdx.x; idx < TOTAL; idx += gridDim.x * 256) {
        float f;
        if (idx < 65536) {
            int e = idx & 7, kc = (idx >> 3) & 3, p = (idx >> 5) & 255, h = idx >> 13;
            int g = h & 3, h2 = h >> 2;
            int i = kc * 8 + e;
            int j = g + 4 * (32 * h2 + i);
            int oc = 4 * (p & 63) + (p >> 6);
            f = ((p >> 6) == g) ? Wk[(oc * IN_C + j) * 9 + 4] : W1[oc * IN_C + j];
        } else {
            int k = idx - 65536;
            int e = k & 7, kc = (k >> 3) & 3, lo = (k >> 5) & 63, tf = (k >> 11) & 7, h = k >> 14;
            int g = h & 3, h2 = h >> 2;
            int i = kc * 8 + e;
            int j = g + 4 * (32 * h2 + i);
            int oc = 4 * lo + g;
            int tfull = tf < 4 ? tf : tf + 1;
            f = Wk[(oc * IN_C + j) * 9 + tfull];
        }
        ws16[idx] = f2bf(f);
    }
}

// ---------------- main kernel helpers ----------------
#define XSPAD 36
#define XSSZ  (4 * 66 * XSPAD)   // 9504 elems per buffer

__device__ __forceinline__ void stage_loads(const float* __restrict__ x, int n, int y0,
                                            int ck, int t, float4 v[4][2]) {
    const int g = ck & 3, h2 = ck >> 2;
    #pragma unroll
    for (int it = 0; it < 4; ++it) {
        int tau = t + it * 256;
        int icp = tau & 15, q = (tau >> 4) & 15, r = tau >> 8;
        int i0 = icp * 2;
        int j0 = g + 4 * (32 * h2 + i0);
        int gy = y0 + r - 1;
        float4 z = {0.f, 0.f, 0.f, 0.f};
        v[it][0] = z; v[it][1] = z;
        if ((unsigned)gy < 64u) {
            const float* p0 = x + (((size_t)n * IN_C + j0) << 12) + (gy << 6) + (q << 2);
            v[it][0] = *(const float4*)p0;
            v[it][1] = *(const float4*)(p0 + 16384);   // plane j0+4
        }
    }
}

__device__ __forceinline__ void stage_writes(int t, float4 v[4][2], unsigned short* __restrict__ xb) {
    #pragma unroll
    for (int it = 0; it < 4; ++it) {
        int tau = t + it * 256;
        int icp = tau & 15, q = (tau >> 4) & 15, r = tau >> 8;
        int i0 = icp * 2;
        unsigned d0 = (unsigned)f2bf(v[it][0].x) | ((unsigned)f2bf(v[it][1].x) << 16);
        unsigned d1 = (unsigned)f2bf(v[it][0].y) | ((unsigned)f2bf(v[it][1].y) << 16);
        unsigned d2 = (unsigned)f2bf(v[it][0].z) | ((unsigned)f2bf(v[it][1].z) << 16);
        unsigned d3 = (unsigned)f2bf(v[it][0].w) | ((unsigned)f2bf(v[it][1].w) << 16);
        int rb = (r * 66 + q * 4 + 1) * XSPAD + i0;
        *(unsigned*)&xb[rb]             = d0;
        *(unsigned*)&xb[rb + XSPAD]     = d1;
        *(unsigned*)&xb[rb + 2 * XSPAD] = d2;
        *(unsigned*)&xb[rb + 3 * XSPAD] = d3;
    }
}

__device__ __forceinline__ bf16x8 lds_bfrag(const unsigned short* __restrict__ xb, int off) {
    bf16x4 lo = *(const bf16x4*)&xb[off];
    bf16x4 hi = *(const bf16x4*)&xb[off + 4];
    return __builtin_shufflevector(lo, hi, 0, 1, 2, 3, 4, 5, 6, 7);
}

template <int G>
__device__ __forceinline__ void compute_chunk(int ck,
        const unsigned short* __restrict__ AH, const unsigned short* __restrict__ AK,
        const unsigned short* __restrict__ xb, f32x4 acc[8][4],
        int mrow, int ncol, int lrow, int kc) {
    const unsigned short* AHh = AH + (ck << 13);
    const unsigned short* AKh = AK + (ck << 14);

    // ---- part A: dense pointwise, K=32 ----
    bf16x8 bfr[4];
    #pragma unroll
    for (int ni = 0; ni < 4; ++ni)
        bfr[ni] = lds_bfrag(xb, ((ncol + 1) * 66 + ni * 16 + lrow + 1) * XSPAD + kc * 8);
    #pragma unroll
    for (int mi = 0; mi < 8; ++mi) {
        int m = mrow + 2 * mi;
        bf16x8 a = *(const bf16x8*)&AHh[((m * 16 + lrow) * 4 + kc) * 8];
        #pragma unroll
        for (int ni = 0; ni < 4; ++ni)
            acc[mi][ni] = __builtin_amdgcn_mfma_f32_16x16x32_bf16(a, bfr[ni], acc[mi][ni], 0, 0, 0);
    }

    // ---- part B: 8 non-center taps, group G only ----
    #pragma unroll
    for (int tf = 0; tf < 8; ++tf) {
        const int tfull = tf < 4 ? tf : tf + 1;
        const int dy = tfull / 3 - 1, dx = tfull % 3 - 1;
        const unsigned short* ak = &AKh[((tf * 64 + mrow * 16 + lrow) * 4 + kc) * 8];
        bf16x8 a0 = *(const bf16x8*)ak;
        bf16x8 a1 = *(const bf16x8*)(ak + 1024);
        #pragma unroll
        for (int ni = 0; ni < 4; ++ni) {
            bf16x8 bb = lds_bfrag(xb, ((ncol + 1 + dy) * 66 + ni * 16 + lrow + 1 + dx) * XSPAD + kc * 8);
            acc[2 * G + 0][ni] = __builtin_amdgcn_mfma_f32_16x16x32_bf16(a0, bb, acc[2 * G + 0][ni], 0, 0, 0);
            acc[2 * G + 1][ni] = __builtin_amdgcn_mfma_f32_16x16x32_bf16(a1, bb, acc[2 * G + 1][ni], 0, 0, 0);
        }
    }
}

// ---------------- main MFMA kernel ----------------
__global__ __launch_bounds__(256, 2)
void hetconv_mfma(const float* __restrict__ x,
                  const unsigned short* __restrict__ wgt,
                  float* __restrict__ out) {
    __shared__ __align__(16) unsigned short xs[2][XSSZ];   // 2 x 19008 B

    const int t    = threadIdx.x;
    const int l    = t & 63;
    const int w    = t >> 6;
    const int mrow = w & 1;
    const int ncol = w >> 1;
    const int lrow = l & 15;
    const int kc   = l >> 4;

    const int bid = blockIdx.x;
    const int n   = (bid & 7) * 4 + (bid >> 8);
    const int y0  = ((bid >> 3) & 31) * 2;

    const unsigned short* AH = wgt;
    const unsigned short* AK = wgt + 65536;

    f32x4 acc[8][4];
    #pragma unroll
    for (int mi = 0; mi < 8; ++mi)
        #pragma unroll
        for (int ni = 0; ni < 4; ++ni) acc[mi][ni] = (f32x4){0.f, 0.f, 0.f, 0.f};

    // ---- prologue: zero halo cols of BOTH buffers + stage chunk 0 ----
    {
        float4 v[4][2];
        stage_loads(x, n, y0, 0, t, v);
        // 256 tasks: buf(2) x r(4) x side(2) x u(16 uints) -> zero elems i=0..31 of cols 0,65
        int buf = t >> 7, r = (t >> 5) & 3, side = (t >> 4) & 1, u = t & 15;
        *(unsigned*)&xs[buf][(r * 66 + side * 65) * XSPAD + u * 2] = 0u;
        stage_writes(t, v, xs[0]);
        __syncthreads();
    }

    // ---- main loop: 2 x (4 static-G bodies), 1 barrier per chunk ----
    #pragma unroll 1
    for (int h2 = 0; h2 < 2; ++h2) {
#define BODY(G)                                                                  \
        {                                                                        \
            const int ck = h2 * 4 + G;                                           \
            const int nc = ck + 1;                                               \
            float4 nv[4][2];                                                     \
            if (G < 3 || h2 == 0) stage_loads(x, n, y0, nc, t, nv);              \
            compute_chunk<G>(ck, AH, AK, xs[G & 1], acc, mrow, ncol, lrow, kc);  \
            if (G < 3 || h2 == 0) stage_writes(t, nv, xs[(G + 1) & 1]);          \
            __syncthreads();                                                     \
        }
        BODY(0) BODY(1) BODY(2) BODY(3)
#undef BODY
    }

    // ---- epilogue: C/D layout col=lane&15, row=(lane>>4)*4+reg ----
    #pragma unroll
    for (int mi = 0; mi < 8; ++mi) {
        int m = mrow + 2 * mi;
        #pragma unroll
        for (int ni = 0; ni < 4; ++ni) {
            #pragma unroll
            for (int reg = 0; reg < 4; ++reg) {
                int p  = m * 16 + kc * 4 + reg;
                int oc = 4 * (p & 63) + (p >> 6);
                out[(((size_t)n * OUT_C + oc) * HH + (y0 + ncol)) * WW + ni * 16 + lrow] = acc[mi][ni][reg];
            }
        }
    }
}

// ---------------- fp32 fallback (only if ws too small) ----------------
#define TH 16
#define TW 16
#define ICC 16
__global__ __launch_bounds__(256)
void hetconv_fp32(const float* __restrict__ x,
                  const float* __restrict__ Wk,
                  const float* __restrict__ W1,
                  float* __restrict__ out) {
    const int t    = threadIdx.x;
    const int g    = blockIdx.y;
    const int n    = blockIdx.z;
    const int tile = blockIdx.x;
    const int ty0  = (tile >> 2) * TH;
    const int tx0  = (tile & 3) * TW;
    const int ol = t & 7;
    const int pl = t >> 3;
    const int r  = pl >> 1;
    const int ch = (pl & 1) * 8;
    __shared__ __align__(16) float xsf[ICC * 18 * 20];
    __shared__ __align__(16) float w1s[ICC * 64];
    __shared__ __align__(16) float wks[4 * 9 * 64];
    float acc[8][8];
    #pragma unroll
    for (int k = 0; k < 8; ++k)
        #pragma unroll
        for (int p = 0; p < 8; ++p) acc[k][p] = 0.f;
    for (int ic0 = 0; ic0 < IN_C; ic0 += ICC) {
        for (int idx = t; idx < ICC * 18 * 18; idx += 256) {
            int ic = idx / 324, rem = idx - ic * 324, rr = rem / 18, cc = rem - rr * 18;
            int gy = ty0 + rr - 1, gx = tx0 + cc - 1;
            float v = 0.f;
            if (gy >= 0 && gy < HH && gx >= 0 && gx < WW)
                v = x[(((size_t)n * IN_C + ic0 + ic) * HH + gy) * WW + gx];
            xsf[ic * 360 + rr * 20 + cc] = v;
        }
        for (int idx = t; idx < ICC * 64; idx += 256) {
            int ic = idx >> 6, o = idx & 63;
            w1s[idx] = W1[(g + 4 * o) * IN_C + ic0 + ic];
        }
        for (int idx = t; idx < 4 * 9 * 64; idx += 256) {
            int a = idx / 576, rem = idx - a * 576, tap = rem >> 6, o = rem & 63;
            wks[idx] = Wk[((g + 4 * o) * IN_C + ic0 + g + 4 * a) * 9 + tap];
        }
        __syncthreads();
        for (int ic = 0; ic < ICC; ++ic) {
            if ((ic & 3) != g) {
                const float* rowp = &xsf[ic * 360 + (r + 1) * 20 + ch];
                float4 A = *(const float4*)rowp;
                float4 B = *(const float4*)(rowp + 4);
                float  c8 = rowp[8];
                float xv[8] = {A.y, A.z, A.w, B.x, B.y, B.z, B.w, c8};
                const float* wp = &w1s[ic * 64 + ol * 8];
                float4 wA = *(const float4*)wp;
                float4 wB = *(const float4*)(wp + 4);
                float wv[8] = {wA.x, wA.y, wA.z, wA.w, wB.x, wB.y, wB.z, wB.w};
                #pragma unroll
                for (int k = 0; k < 8; ++k)
                    #pragma unroll
                    for (int p = 0; p < 8; ++p) acc[k][p] += wv[k] * xv[p];
            } else {
                const int a = ic >> 2;
                #pragma unroll
                for (int dy = -1; dy <= 1; ++dy) {
                    const float* rowp = &xsf[ic * 360 + (r + 1 + dy) * 20 + ch];
                    float4 A = *(const float4*)rowp;
                    float4 B = *(const float4*)(rowp + 4);
                    float2 C = *(const float2*)(rowp + 8);
                    float seg[10] = {A.x, A.y, A.z, A.w, B.x, B.y, B.z, B.w, C.x, C.y};
                    #pragma unroll
                    for (int dxi = 0; dxi < 3; ++dxi) {
                        const float* wp = &wks[(a * 9 + (dy + 1) * 3 + dxi) * 64 + ol * 8];
                        float4 wA = *(const float4*)wp;
                        float4 wB = *(const float4*)(wp + 4);
                        float wv[8] = {wA.x, wA.y, wA.z, wA.w, wB.x, wB.y, wB.z, wB.w};
                        #pragma unroll
                        for (int k = 0; k < 8; ++k)
                            #pragma unroll
                            for (int p = 0; p < 8; ++p) acc[k][p] += wv[k] * seg[p + dxi];
                    }
                }
            }
        }
        __syncthreads();
    }
    #pragma unroll
    for (int k = 0; k < 8; ++k) {
        int oc = g + 4 * (ol * 8 + k);
        size_t base = (((size_t)n * OUT_C + oc) * HH + (ty0 + r)) * WW + tx0 + ch;
        float4 v0 = {acc[k][0], acc[k][1], acc[k][2], acc[k][3]};
        float4 v1 = {acc[k][4], acc[k][5], acc[k][6], acc[k][7]};
        *(float4*)(&out[base])     = v0;
        *(float4*)(&out[base + 4]) = v1;
    }
}

extern "C" void kernel_launch(void* const* d_in, const int* in_sizes, int n_in,
                              void* d_out, int out_size, void* d_ws, size_t ws_size,
                              hipStream_t stream) {
    const float* x  = (const float*)d_in[0];
    const float* Wk = (const float*)d_in[1];
    const float* W1 = (const float*)d_in[2];
    float* outp = (float*)d_out;

    if (ws_size >= (size_t)(65536 + 131072) * sizeof(unsigned short)) {
        hetconv_prep<<<256, 256, 0, stream>>>(Wk, W1, (unsigned short*)d_ws);
        hetconv_mfma<<<1024, 256, 0, stream>>>(x, (const unsigned short*)d_ws, outp);
    } else {
        hetconv_fp32<<<dim3(16, 4, 32), 256, 0, stream>>>(x, Wk, W1, outp);
    }
}